// Round 1
// baseline (159.428 us; speedup 1.0000x reference)
//
#include <hip/hip_runtime.h>

// Multi-level db4 DWT (pywt wavedec, symmetric, level=4).
// Input  trajectory: [B=16, T=4096, F=256] f32, feature-fastest.
// Output: [B, T, 5, F] f32; bands [cA4, cD4, cD3, cD2, cD1], each zero-padded to T.
//
// Per level with input length L: Lo = (L+7)/2 outputs;
//   out[n] = sum_{k=0..7} x_sym[2n+k-6] * DEC[7-k]
//   where x_sym reflects: i<0 -> -1-i ; i>=L -> 2L-1-i   (single bounce, FLEN-1 < L always)
// RLO[k] = DEC_LO[7-k]; RHI[k] = (-1)^k * DEC_LO[k]  (derived from pywt QMF relation).

namespace {
constexpr int T_LEN  = 4096;
constexpr int F_DIM  = 256;
constexpr int NBANDS = 5;
}

__device__ __constant__ float RLO[8] = {
     0.23037781330885523f,   0.7148465705525415f,   0.6308807679295904f,
    -0.02798376941698385f,  -0.18703481171888114f,  0.030841381835986965f,
     0.032883011666982945f, -0.010597401784997278f };

__device__ __constant__ float RHI[8] = {
    -0.010597401784997278f, -0.032883011666982945f, 0.030841381835986965f,
     0.18703481171888114f,  -0.02798376941698385f, -0.6308807679295904f,
     0.7148465705525415f,   -0.23037781330885523f };

// One block per (b, t) output row; 256 threads = 256 features (fully coalesced).
// Computes one DWT level: writes cA to cA_out (if !final_level) for rows t<Lout,
// and writes the cD band (zero-padded over t in [Lout, T)) into the output tensor.
// If final_level, also writes cA into band 0 (zero-padded).
extern "C" __global__ __launch_bounds__(256)
void dwt_level(const float* __restrict__ in, float* __restrict__ cA_out,
               float* __restrict__ out, int Lin, int Lout, int bandD, int final_level)
{
    const int f  = threadIdx.x;
    const int bt = blockIdx.x;
    const int t  = bt & (T_LEN - 1);
    const int b  = bt >> 12;            // T_LEN == 4096

    float a = 0.f, d = 0.f;
    if (t < Lout) {
        const float* inb = in + ((size_t)b * Lin) * F_DIM + f;
        #pragma unroll
        for (int k = 0; k < 8; ++k) {
            int i = 2 * t + k - 6;                 // signal index (may be out of range)
            i = (i < 0)    ? (-1 - i)        : i;  // left symmetric reflection
            i = (i >= Lin) ? (2 * Lin - 1 - i) : i; // right symmetric reflection
            float v = inb[(size_t)i * F_DIM];
            a = fmaf(v, RLO[k], a);
            d = fmaf(v, RHI[k], d);
        }
        if (!final_level)
            cA_out[((size_t)b * Lout + t) * F_DIM + f] = a;
    }
    const size_t ob = (((size_t)b * T_LEN + t) * NBANDS) * F_DIM + (size_t)f;
    out[ob + (size_t)bandD * F_DIM] = (t < Lout) ? d : 0.f;
    if (final_level)
        out[ob] = (t < Lout) ? a : 0.f;   // cA4 -> band 0
}

extern "C" void kernel_launch(void* const* d_in, const int* in_sizes, int n_in,
                              void* d_out, int out_size, void* d_ws, size_t ws_size,
                              hipStream_t stream)
{
    const float* traj = (const float*)d_in[0];
    float* out = (float*)d_out;

    const int B  = 16;
    const int L0 = 4096;          // input length
    const int L1 = 2051;          // (4096+7)/2
    const int L2 = 1029;          // (2051+7)/2
    const int L3 = 518;           // (1029+7)/2
    const int L4 = 262;           // (518+7)/2

    // Workspace ping-pong: cA1 -> ws0, cA2 -> ws1, cA3 -> ws0 (fits: L3 < L1).
    // Requires B*(L1+L2)*F*4 = 50,462,720 bytes of d_ws.
    float* ws0 = (float*)d_ws;
    float* ws1 = ws0 + (size_t)B * L1 * F_DIM;

    dim3 grid(B * T_LEN), block(F_DIM);
    hipLaunchKernelGGL(dwt_level, grid, block, 0, stream, traj, ws0, out, L0, L1, 4, 0);
    hipLaunchKernelGGL(dwt_level, grid, block, 0, stream, ws0,  ws1, out, L1, L2, 3, 0);
    hipLaunchKernelGGL(dwt_level, grid, block, 0, stream, ws1,  ws0, out, L2, L3, 2, 0);
    hipLaunchKernelGGL(dwt_level, grid, block, 0, stream, ws0,  (float*)nullptr, out, L3, L4, 1, 1);
}

// Round 2
// 105.094 us; speedup vs baseline: 1.5170x; 1.5170x over previous
//
#include <hip/hip_runtime.h>

// Multi-level db4 DWT (pywt wavedec, symmetric, level=4).
// Input  trajectory: [B=16, T=4096, F=256] f32, feature-fastest.
// Output: [B, T, 5, F] f32; bands [cA4, cD4, cD3, cD2, cD1], each zero-padded to T.
//
// Per level with input length L: Lo = (L+7)/2 outputs;
//   out[n] = sum_{k=0..7} x_sym[2n+k-6] * DEC[7-k]
//   reflect: i<0 -> -1-i ; i>=L -> 2L-1-i  (single bounce suffices for all levels)
// RLO[k] = DEC_LO[7-k]; RHI[k] = (-1)^k * DEC_LO[k].
//
// R2: 16-row t-tiles per block (read amp 38/32 vs 8/1) + bijective XCD-chunked
// swizzle so halo rows shared by neighboring tiles hit the same XCD's L2.

namespace {
constexpr int T_LEN  = 4096;
constexpr int F_DIM  = 256;
constexpr int NBANDS = 5;
constexpr int TT     = 16;                 // t-rows per block
constexpr int NTILES = T_LEN / TT;         // 256
}

__device__ __constant__ float RLO[8] = {
     0.23037781330885523f,   0.7148465705525415f,   0.6308807679295904f,
    -0.02798376941698385f,  -0.18703481171888114f,  0.030841381835986965f,
     0.032883011666982945f, -0.010597401784997278f };

__device__ __constant__ float RHI[8] = {
    -0.010597401784997278f, -0.032883011666982945f, 0.030841381835986965f,
     0.18703481171888114f,  -0.02798376941698385f, -0.6308807679295904f,
     0.7148465705525415f,   -0.23037781330885523f };

// 256 threads = 256 features; block handles (b, t0..t0+TT-1).
extern "C" __global__ __launch_bounds__(256)
void dwt_level_tiled(const float* __restrict__ in, float* __restrict__ cA_out,
                     float* __restrict__ out, int Lin, int Lout, int bandD,
                     int final_level)
{
    const int f = threadIdx.x;

    // bijective XCD-chunk swizzle: gridDim.x = 4096 (divisible by 8)
    const int per = gridDim.x >> 3;
    const int wg  = (blockIdx.x & 7) * per + (blockIdx.x >> 3);
    const int b   = wg / NTILES;
    const int t0  = (wg % NTILES) * TT;

    const size_t row_stride = (size_t)NBANDS * F_DIM;
    const size_t orow = (((size_t)b * T_LEN + t0) * NBANDS) * F_DIM + (size_t)f;

    if (t0 >= Lout) {                       // pure zero tile: no loads
        #pragma unroll
        for (int j = 0; j < TT; ++j) {
            out[orow + (size_t)j * row_stride + (size_t)bandD * F_DIM] = 0.f;
            if (final_level)
                out[orow + (size_t)j * row_stride] = 0.f;
        }
        return;
    }

    const float* inb = in + (size_t)b * Lin * F_DIM + f;
    float x[2 * TT + 6];
    #pragma unroll
    for (int r = 0; r < 2 * TT + 6; ++r) {
        int i = 2 * t0 - 6 + r;
        i = (i < 0)     ? (-1 - i)          : i;   // left reflect
        i = (i >= Lin)  ? (2 * Lin - 1 - i) : i;   // right reflect
        x[r] = inb[(size_t)i * F_DIM];
    }

    #pragma unroll
    for (int j = 0; j < TT; ++j) {
        const int t = t0 + j;
        float a = 0.f, d = 0.f;
        #pragma unroll
        for (int k = 0; k < 8; ++k) {
            const float v = x[2 * j + k];
            a = fmaf(v, RLO[k], a);
            d = fmaf(v, RHI[k], d);
        }
        const bool live = (t < Lout);
        if (live && !final_level)
            cA_out[((size_t)b * Lout + t) * F_DIM + f] = a;
        out[orow + (size_t)j * row_stride + (size_t)bandD * F_DIM] = live ? d : 0.f;
        if (final_level)
            out[orow + (size_t)j * row_stride] = live ? a : 0.f;
    }
}

extern "C" void kernel_launch(void* const* d_in, const int* in_sizes, int n_in,
                              void* d_out, int out_size, void* d_ws, size_t ws_size,
                              hipStream_t stream)
{
    const float* traj = (const float*)d_in[0];
    float* out = (float*)d_out;

    const int B  = 16;
    const int L0 = 4096;
    const int L1 = 2051;          // (4096+7)/2
    const int L2 = 1029;          // (2051+7)/2
    const int L3 = 518;           // (1029+7)/2
    const int L4 = 262;           // (518+7)/2

    // ws ping-pong: cA1 -> ws0, cA2 -> ws1, cA3 -> ws0 (L3 < L1 so it fits).
    float* ws0 = (float*)d_ws;
    float* ws1 = ws0 + (size_t)B * L1 * F_DIM;

    dim3 grid(B * NTILES), block(F_DIM);   // 4096 blocks, divisible by 8
    hipLaunchKernelGGL(dwt_level_tiled, grid, block, 0, stream, traj, ws0, out, L0, L1, 4, 0);
    hipLaunchKernelGGL(dwt_level_tiled, grid, block, 0, stream, ws0,  ws1, out, L1, L2, 3, 0);
    hipLaunchKernelGGL(dwt_level_tiled, grid, block, 0, stream, ws1,  ws0, out, L2, L3, 2, 0);
    hipLaunchKernelGGL(dwt_level_tiled, grid, block, 0, stream, ws0,  (float*)nullptr, out, L3, L4, 1, 1);
}

// Round 3
// 77.326 us; speedup vs baseline: 2.0618x; 1.3591x over previous
//
#include <hip/hip_runtime.h>

// Multi-level db4 DWT (pywt wavedec, symmetric, level=4), fused pairwise.
// Input  trajectory: [B=16, T=4096, F=256] f32, feature-fastest.
// Output: [B, T, 5, F] f32; bands [cA4, cD4, cD3, cD2, cD1], zero-padded to T.
//
// Lengths: L1=2051, L2=1029, L3=518, L4=262  (Lo = (L+7)/2).
// out[n] = sum_k x_sym[2n+k-6] * DEC[7-k]; reflect i<0 -> -1-i, i>=L -> 2L-1-i.
// Reflection applies to the COEFFICIENT array at each level (does not commute
// through levels) -> keep the cA tile addressable by runtime reflected index.
// Register arrays can't take runtime indices (scratch spill), so the cA tile
// lives in LDS; thread f only ever touches column f -> conflict-free.

namespace {
constexpr int T_LEN = 4096;
constexpr int F_DIM = 256;
constexpr int NB    = 5;
constexpr int L1 = 2051, L2 = 1029, L3 = 518, L4 = 262;
}

__device__ __constant__ float RLO[8] = {
     0.23037781330885523f,   0.7148465705525415f,   0.6308807679295904f,
    -0.02798376941698385f,  -0.18703481171888114f,  0.030841381835986965f,
     0.032883011666982945f, -0.010597401784997278f };

__device__ __constant__ float RHI[8] = {
    -0.010597401784997278f, -0.032883011666982945f, 0.030841381835986965f,
     0.18703481171888114f,  -0.02798376941698385f, -0.6308807679295904f,
     0.7148465705525415f,   -0.23037781330885523f };

__device__ __forceinline__ void nt_store(float* p, float v) {
    __builtin_nontemporal_store(v, p);
}

// ---------------- Kernel A: levels 1+2 ----------------
// grid = 16 b * 256 tiles; block owns t1 in [16k,16k+16), t2 in [8k,8k+8)
// (plus the always-zero mirror rows t2+2048 of band 3).
extern "C" __global__ __launch_bounds__(256)
void dwt_l12(const float* __restrict__ in, float* __restrict__ cA2,
             float* __restrict__ out)
{
    const int f   = threadIdx.x;
    const int per = gridDim.x >> 3;                       // bijective XCD swizzle
    const int wg  = (blockIdx.x & 7) * per + (blockIdx.x >> 3);
    const int b   = wg >> 8;
    const int k   = wg & 255;

    float* outb = out + ((size_t)b * T_LEN * NB) * F_DIM + f;
    const int t1o = 16 * k;
    const int t2o = 8 * k;

    if (k > 128) {                                        // fully dead tile
        #pragma unroll
        for (int m = 0; m < 16; ++m)
            nt_store(&outb[((size_t)(t1o + m) * NB + 4) * F_DIM], 0.f);
        #pragma unroll
        for (int n = 0; n < 8; ++n) {
            nt_store(&outb[((size_t)(t2o + n) * NB + 3) * F_DIM], 0.f);
            nt_store(&outb[((size_t)(t2o + n + 2048) * NB + 3) * F_DIM], 0.f);
        }
        return;
    }

    const float* inb = in + (size_t)b * T_LEN * F_DIM + f;
    const int t1base = t1o - 6;
    const int gbase  = 2 * t1base - 6;                    // 32k - 18

    float x[50];                                          // input rows (static idx)
    #pragma unroll
    for (int r = 0; r < 50; ++r) {
        int g = gbase + r;
        g = (g < 0)      ? (-1 - g)            : g;
        g = (g >= T_LEN) ? (2 * T_LEN - 1 - g) : g;
        x[r] = inb[(size_t)g * F_DIM];
    }

    __shared__ float aTile[22 * F_DIM];                   // cA1 rows [t1base, t1base+22)

    #pragma unroll
    for (int r = 0; r < 22; ++r) {
        float a = 0.f, d = 0.f;
        #pragma unroll
        for (int kk = 0; kk < 8; ++kk) {
            a = fmaf(x[2 * r + kk], RLO[kk], a);
            d = fmaf(x[2 * r + kk], RHI[kk], d);
        }
        aTile[r * F_DIM + f] = a;
        if (r >= 6) {                                     // owned cD1 row
            const int t1 = t1base + r;
            nt_store(&outb[((size_t)t1 * NB + 4) * F_DIM], (t1 < L1) ? d : 0.f);
        }
    }
    __syncthreads();                                      // LDS ordering safety

    #pragma unroll
    for (int n = 0; n < 8; ++n) {
        const int t2 = t2o + n;
        float a = 0.f, d = 0.f;
        #pragma unroll
        for (int kk = 0; kk < 8; ++kk) {
            int i = 2 * t2 + kk - 6;
            i = (i < 0)   ? (-1 - i)         : i;
            i = (i >= L1) ? (2 * L1 - 1 - i) : i;
            const float v = aTile[(i - t1base) * F_DIM + f];
            a = fmaf(v, RLO[kk], a);
            d = fmaf(v, RHI[kk], d);
        }
        nt_store(&outb[((size_t)t2 * NB + 3) * F_DIM], (t2 < L2) ? d : 0.f);
        nt_store(&outb[((size_t)(t2 + 2048) * NB + 3) * F_DIM], 0.f);
        if (t2 < L2)
            cA2[((size_t)b * L2 + t2) * F_DIM + f] = a;   // plain store: re-read by B
    }
}

// ---------------- Kernel B: levels 3+4 ----------------
// grid = 16 b * 512 tiles; block owns t3 in [8k,8k+8), t4 in [4k,4k+4)
// (plus zero mirrors t4+2048 of bands 0,1).
extern "C" __global__ __launch_bounds__(256)
void dwt_l34(const float* __restrict__ cA2, float* __restrict__ out)
{
    const int f   = threadIdx.x;
    const int per = gridDim.x >> 3;
    const int wg  = (blockIdx.x & 7) * per + (blockIdx.x >> 3);
    const int b   = wg >> 9;
    const int k   = wg & 511;

    float* outb = out + ((size_t)b * T_LEN * NB) * F_DIM + f;
    const int t3o = 8 * k;
    const int t4o = 4 * k;

    if (k > 65) {                                         // fully dead tile
        #pragma unroll
        for (int n = 0; n < 8; ++n)
            nt_store(&outb[((size_t)(t3o + n) * NB + 2) * F_DIM], 0.f);
        #pragma unroll
        for (int m = 0; m < 4; ++m) {
            nt_store(&outb[((size_t)(t4o + m) * NB + 1) * F_DIM], 0.f);
            nt_store(&outb[((size_t)(t4o + m) * NB + 0) * F_DIM], 0.f);
            nt_store(&outb[((size_t)(t4o + m + 2048) * NB + 1) * F_DIM], 0.f);
            nt_store(&outb[((size_t)(t4o + m + 2048) * NB + 0) * F_DIM], 0.f);
        }
        return;
    }

    const float* inb = cA2 + (size_t)b * L2 * F_DIM + f;
    const int t3base = t3o - 8;       // 16-row tile: right-edge reflection reaches 8k-8
    const int gbase  = 2 * t3base - 6;                    // 16k - 22

    float x[38];
    #pragma unroll
    for (int r = 0; r < 38; ++r) {
        int g = gbase + r;
        g = (g < 0)   ? (-1 - g)         : g;
        g = (g >= L2) ? (2 * L2 - 1 - g) : g;
        x[r] = inb[(size_t)g * F_DIM];
    }

    __shared__ float aTile[16 * F_DIM];                   // cA3 rows [t3base, t3base+16)

    #pragma unroll
    for (int r = 0; r < 16; ++r) {
        float a = 0.f, d = 0.f;
        #pragma unroll
        for (int kk = 0; kk < 8; ++kk) {
            a = fmaf(x[2 * r + kk], RLO[kk], a);
            d = fmaf(x[2 * r + kk], RHI[kk], d);
        }
        aTile[r * F_DIM + f] = a;
        if (r >= 8) {                                     // owned cD3 row
            const int t3 = t3base + r;
            nt_store(&outb[((size_t)t3 * NB + 2) * F_DIM], (t3 < L3) ? d : 0.f);
        }
    }
    __syncthreads();

    #pragma unroll
    for (int m = 0; m < 4; ++m) {
        const int t4 = t4o + m;
        float a = 0.f, d = 0.f;
        #pragma unroll
        for (int kk = 0; kk < 8; ++kk) {
            int i = 2 * t4 + kk - 6;
            i = (i < 0)   ? (-1 - i)         : i;
            i = (i >= L3) ? (2 * L3 - 1 - i) : i;
            const float v = aTile[(i - t3base) * F_DIM + f];
            a = fmaf(v, RLO[kk], a);
            d = fmaf(v, RHI[kk], d);
        }
        nt_store(&outb[((size_t)t4 * NB + 1) * F_DIM], (t4 < L4) ? d : 0.f);
        nt_store(&outb[((size_t)t4 * NB + 0) * F_DIM], (t4 < L4) ? a : 0.f);
        nt_store(&outb[((size_t)(t4 + 2048) * NB + 1) * F_DIM], 0.f);
        nt_store(&outb[((size_t)(t4 + 2048) * NB + 0) * F_DIM], 0.f);
    }
}

extern "C" void kernel_launch(void* const* d_in, const int* in_sizes, int n_in,
                              void* d_out, int out_size, void* d_ws, size_t ws_size,
                              hipStream_t stream)
{
    const float* traj = (const float*)d_in[0];
    float* out = (float*)d_out;
    float* cA2 = (float*)d_ws;        // 16*1029*256*4 = 16.86 MB

    dim3 block(F_DIM);
    hipLaunchKernelGGL(dwt_l12, dim3(16 * 256), block, 0, stream, traj, cA2, out);
    hipLaunchKernelGGL(dwt_l34, dim3(16 * 512), block, 0, stream, cA2, out);
}

// Round 4
// 71.500 us; speedup vs baseline: 2.2298x; 1.0815x over previous
//
#include <hip/hip_runtime.h>

// Fully-fused 4-level db4 DWT (pywt wavedec, symmetric, level=4).
// Input  trajectory: [B=16, T=4096, F=256] f32, feature-fastest.
// Output: [B, T, 5, F] f32; bands [cA4, cD4, cD3, cD2, cD1], zero-padded to T.
//
// One kernel, grid = 16 b x 128 k. Block k owns t1[32k,32k+32) t2[16k,16k+16)
// t3[8k,8k+8) t4[4k,4k+4) plus fixed all-zero mirror rows so every output row
// is written exactly once. Whole cascade per-thread in registers (thread =
// feature column, no cross-thread data -> no LDS). Reflection only occurs in
// blocks k in {0,1,64,65}; those get exact-k template instantiations where all
// reflected tap indices constant-fold (register arrays need static indices).
// Interior k in [2,63] is reflection-free (tap ranges verified in-bounds).
// k >= 66: pure zero stores.
//
// out[n] = sum_j x_sym[2n+j-6] * DEC[7-j]; refl: i<0 -> -1-i, i>=L -> 2L-1-i.
// Lengths: L1=2051, L2=1029, L3=518, L4=262.

namespace {
constexpr int T_LEN = 4096;
constexpr int F_DIM = 256;
constexpr int NB    = 5;
constexpr int L1 = 2051, L2 = 1029, L3 = 518, L4 = 262;
}

__device__ __constant__ float RLO[8] = {
     0.23037781330885523f,   0.7148465705525415f,   0.6308807679295904f,
    -0.02798376941698385f,  -0.18703481171888114f,  0.030841381835986965f,
     0.032883011666982945f, -0.010597401784997278f };

__device__ __constant__ float RHI[8] = {
    -0.010597401784997278f, -0.032883011666982945f, 0.030841381835986965f,
     0.18703481171888114f,  -0.02798376941698385f, -0.6308807679295904f,
     0.7148465705525415f,   -0.23037781330885523f };

__device__ __host__ constexpr int refl(int i, int L) {
    return (i < 0) ? (-1 - i) : ((i >= L) ? (2 * L - 1 - i) : i);
}

__device__ __forceinline__ void nt_store(float* p, float v) {
    __builtin_nontemporal_store(v, p);
}

// Zero rows: owned-but-dead tails + all mirror rows. Disjoint from cascade stores.
__device__ __forceinline__ void zero_pass(float* __restrict__ outb, int k)
{
    const int o1 = 32 * k, o2 = 16 * k, o3 = 8 * k, o4 = 4 * k;
    const int lv1 = max(0, min(32, L1 - o1));
    const int lv2 = max(0, min(16, L2 - o2));
    const int lv3 = max(0, min(8,  L3 - o3));
    const int lv4 = max(0, min(4,  L4 - o4));
    for (int r = lv1; r < 32; ++r) nt_store(outb + ((size_t)(o1 + r) * NB + 4) * F_DIM, 0.f);
    for (int r = lv2; r < 16; ++r) nt_store(outb + ((size_t)(o2 + r) * NB + 3) * F_DIM, 0.f);
    #pragma unroll
    for (int r = 0; r < 16; ++r)   nt_store(outb + ((size_t)(o2 + 2048 + r) * NB + 3) * F_DIM, 0.f);
    for (int r = lv3; r < 8; ++r)  nt_store(outb + ((size_t)(o3 + r) * NB + 2) * F_DIM, 0.f);
    #pragma unroll
    for (int j = 1; j < 4; ++j)
        #pragma unroll
        for (int r = 0; r < 8; ++r)
            nt_store(outb + ((size_t)(o3 + 1024 * j + r) * NB + 2) * F_DIM, 0.f);
    for (int r = lv4; r < 4; ++r) {
        nt_store(outb + ((size_t)(o4 + r) * NB + 1) * F_DIM, 0.f);
        nt_store(outb + ((size_t)(o4 + r) * NB + 0) * F_DIM, 0.f);
    }
    #pragma unroll
    for (int j = 1; j < 8; ++j)
        #pragma unroll
        for (int r = 0; r < 4; ++r) {
            nt_store(outb + ((size_t)(o4 + 512 * j + r) * NB + 1) * F_DIM, 0.f);
            nt_store(outb + ((size_t)(o4 + 512 * j + r) * NB + 0) * F_DIM, 0.f);
        }
}

// KX: -1 = interior (runtime k in [2,63], no reflection anywhere);
//     0,1,64,65 = exact-k edge specializations (reflection constant-folded).
template<int KX>
__device__ __forceinline__ void cascade(const float* __restrict__ inb,
                                        float* __restrict__ outb, int krt)
{
    constexpr bool EX = (KX >= 0);
    constexpr bool DP = (KX == 65);               // k=65 needs 2-row-deeper cA3 tile
    constexpr int N1 = DP ? 82 : 74, N2 = DP ? 38 : 34, N3 = DP ? 16 : 14;
    constexpr int OWN1 = DP ? 50 : 42, OWN2 = DP ? 22 : 18, OWN3 = DP ? 8 : 6;
    constexpr int R1LO = (KX == 0) ? 42 : (KX == 1) ? 10 : 0;
    constexpr int R1HI = (KX == 64) ? 45 : (KX == 65) ? 21 : N1;
    constexpr int R2LO = (KX == 0) ? 18 : (KX == 1) ? 2 : 0;
    constexpr int R2HI = (KX == 64) ? 23 : (KX == 65) ? 11 : N2;
    constexpr int R3LO = (KX == 0) ? 6 : 0;
    constexpr int R3HI = (KX == 64) ? 12 : (KX == 65) ? 6 : N3;
    constexpr int MHI  = (KX == 65) ? 2 : 4;

    const int k   = EX ? KX : krt;
    const int t1b = 32 * k - (DP ? 50 : 42);
    const int t2b = 16 * k - (DP ? 22 : 18);
    const int t3b = 8 * k  - (DP ? 8  : 6);

    float A[N1], B[N2], C[N3];

    // ---- level 1: input -> cA1 (A[]) + cD1 stores; 8-deep input shift window ----
    float xw[8];
    #pragma unroll
    for (int j = 0; j < 8; ++j) {
        int g = 2 * (t1b + R1LO) - 6 + j;
        if (EX) g = refl(g, T_LEN);
        xw[j] = inb[(size_t)g * F_DIM];
    }
    #pragma unroll
    for (int r1 = R1LO; r1 < R1HI; ++r1) {
        float a = 0.f, d = 0.f;
        #pragma unroll
        for (int j = 0; j < 8; ++j) { a = fmaf(xw[j], RLO[j], a); d = fmaf(xw[j], RHI[j], d); }
        A[r1] = a;
        const int t1 = t1b + r1;
        if (r1 >= OWN1)
            nt_store(outb + ((size_t)t1 * NB + 4) * F_DIM, d);
        if (r1 + 1 < R1HI) {
            #pragma unroll
            for (int j = 0; j < 6; ++j) xw[j] = xw[j + 2];
            int g6 = 2 * t1 + 2, g7 = 2 * t1 + 3;
            if (EX) { g6 = refl(g6, T_LEN); g7 = refl(g7, T_LEN); }
            xw[6] = inb[(size_t)g6 * F_DIM];
            xw[7] = inb[(size_t)g7 * F_DIM];
        }
    }

    // ---- level 2: cA1 -> cA2 (B[]) + cD2 stores ----
    #pragma unroll
    for (int r2 = R2LO; r2 < R2HI; ++r2) {
        float a = 0.f, d = 0.f;
        #pragma unroll
        for (int j = 0; j < 8; ++j) {
            const int i1 = EX ? (refl(2 * (t2b + r2) - 6 + j, L1) - t1b) : (2 * r2 + j);
            const float v = A[i1];
            a = fmaf(v, RLO[j], a); d = fmaf(v, RHI[j], d);
        }
        B[r2] = a;
        if (r2 >= OWN2)
            nt_store(outb + ((size_t)(t2b + r2) * NB + 3) * F_DIM, d);
    }

    // ---- level 3: cA2 -> cA3 (C[]) + cD3 stores ----
    #pragma unroll
    for (int r3 = R3LO; r3 < R3HI; ++r3) {
        float a = 0.f, d = 0.f;
        #pragma unroll
        for (int j = 0; j < 8; ++j) {
            const int i2 = EX ? (refl(2 * (t3b + r3) - 6 + j, L2) - t2b) : (2 * r3 + j);
            const float v = B[i2];
            a = fmaf(v, RLO[j], a); d = fmaf(v, RHI[j], d);
        }
        C[r3] = a;
        if (r3 >= OWN3)
            nt_store(outb + ((size_t)(t3b + r3) * NB + 2) * F_DIM, d);
    }

    // ---- level 4: cA3 -> cA4 (band 0) + cD4 (band 1) stores ----
    #pragma unroll
    for (int m = 0; m < MHI; ++m) {
        float a = 0.f, d = 0.f;
        #pragma unroll
        for (int j = 0; j < 8; ++j) {
            const int i3 = EX ? (refl(2 * (4 * k + m) - 6 + j, L3) - t3b) : (2 * m + j);
            const float v = C[i3];
            a = fmaf(v, RLO[j], a); d = fmaf(v, RHI[j], d);
        }
        const int t4 = 4 * k + m;
        nt_store(outb + ((size_t)t4 * NB + 1) * F_DIM, d);
        nt_store(outb + ((size_t)t4 * NB + 0) * F_DIM, a);
    }
}

extern "C" __global__ __launch_bounds__(256)
void dwt_fused(const float* __restrict__ in, float* __restrict__ out)
{
    const int f   = threadIdx.x;
    const int per = gridDim.x >> 3;                      // bijective XCD swizzle (2048 % 8 == 0)
    const int wg  = (int)(blockIdx.x & 7) * per + (int)(blockIdx.x >> 3);
    const int b   = wg >> 7;                             // 128 k-tiles per batch
    const int k   = wg & 127;

    float* outb = out + (size_t)b * T_LEN * NB * F_DIM + f;
    zero_pass(outb, k);
    if (k >= 66) return;                                 // fully dead tile

    const float* inb = in + (size_t)b * T_LEN * F_DIM + f;
    switch (k) {
        case 0:  cascade<0 >(inb, outb, k); break;
        case 1:  cascade<1 >(inb, outb, k); break;
        case 64: cascade<64>(inb, outb, k); break;
        case 65: cascade<65>(inb, outb, k); break;
        default: cascade<-1>(inb, outb, k); break;       // interior: k in [2,63]
    }
}

extern "C" void kernel_launch(void* const* d_in, const int* in_sizes, int n_in,
                              void* d_out, int out_size, void* d_ws, size_t ws_size,
                              hipStream_t stream)
{
    const float* traj = (const float*)d_in[0];
    float* out = (float*)d_out;
    hipLaunchKernelGGL(dwt_fused, dim3(16 * 128), dim3(F_DIM), 0, stream, traj, out);
}

// Round 5
// 71.351 us; speedup vs baseline: 2.2344x; 1.0021x over previous
//
#include <hip/hip_runtime.h>

// Fully-fused 4-level db4 DWT (pywt wavedec, symmetric, level=4).
// Input  trajectory: [B=16, T=4096, F=256] f32, feature-fastest.
// Output: [B, T, 5, F] f32; bands [cA4, cD4, cD3, cD2, cD1], zero-padded to T.
//
// One kernel, grid = 16 b x 128 slots. Slots 0..65: live cascade tiles
// (whole 4-level cascade per-thread in registers; reflection only in
// k in {0,1,64,65}, handled by exact-k template instantiations so all
// reflected indices constant-fold). Slots 66..127: zero-fill blocks.
// Zeros form per-row contiguous PREFIXES (bands die in order cA4,cD4,cD3,
// cD2,cD1 as t grows): [262,518)->2KB, [518,1029)->3KB, [1029,2051)->4KB,
// [2051,4096)->5KB. Fill blocks write them as nontemporal dwordx4 at
// ~255KB/block, matching live-block traffic -> load-balanced grid.
//
// out[n] = sum_j x_sym[2n+j-6] * DEC[7-j]; refl: i<0 -> -1-i, i>=L -> 2L-1-i.
// Lengths: L1=2051, L2=1029, L3=518, L4=262.

namespace {
constexpr int T_LEN = 4096;
constexpr int F_DIM = 256;
constexpr int NB    = 5;
constexpr int L1 = 2051, L2 = 1029, L3 = 518, L4 = 262;
}

typedef float f32x4 __attribute__((ext_vector_type(4)));

__device__ __constant__ float RLO[8] = {
     0.23037781330885523f,   0.7148465705525415f,   0.6308807679295904f,
    -0.02798376941698385f,  -0.18703481171888114f,  0.030841381835986965f,
     0.032883011666982945f, -0.010597401784997278f };

__device__ __constant__ float RHI[8] = {
    -0.010597401784997278f, -0.032883011666982945f, 0.030841381835986965f,
     0.18703481171888114f,  -0.02798376941698385f, -0.6308807679295904f,
     0.7148465705525415f,   -0.23037781330885523f };

__device__ __host__ constexpr int refl(int i, int L) {
    return (i < 0) ? (-1 - i) : ((i >= L) ? (2 * L - 1 - i) : i);
}

__device__ __forceinline__ void nt_store(float* p, float v) {
    __builtin_nontemporal_store(v, p);
}

// ---- zero-fill: rows [t0,t1) each get a Z*1KB zero prefix (dwordx4) ----
template<int Z>
__device__ __forceinline__ void fill_zeros(float* __restrict__ outB,
                                           int t0, int t1, int tid)
{
    const f32x4 z4 = {0.f, 0.f, 0.f, 0.f};
    for (int t = t0; t < t1; ++t) {
        float* row = outB + (size_t)t * NB * F_DIM;
        #pragma unroll
        for (int c0 = 0; c0 < Z * F_DIM; c0 += 4 * F_DIM) {
            const int c = c0 + tid * 4;
            if (c < Z * F_DIM)
                __builtin_nontemporal_store(z4, (f32x4*)(row + c));
        }
    }
}

// KX: -1 = interior (runtime k in [2,63], no reflection anywhere);
//     0,1,64,65 = exact-k edge specializations (reflection constant-folded).
template<int KX>
__device__ __forceinline__ void cascade(const float* __restrict__ inb,
                                        float* __restrict__ outb, int krt)
{
    constexpr bool EX = (KX >= 0);
    constexpr bool DP = (KX == 65);               // k=65 needs 2-row-deeper cA3 tile
    constexpr int N1 = DP ? 82 : 74, N2 = DP ? 38 : 34, N3 = DP ? 16 : 14;
    constexpr int OWN1 = DP ? 50 : 42, OWN2 = DP ? 22 : 18, OWN3 = DP ? 8 : 6;
    constexpr int R1LO = (KX == 0) ? 42 : (KX == 1) ? 10 : 0;
    constexpr int R1HI = (KX == 64) ? 45 : (KX == 65) ? 21 : N1;
    constexpr int R2LO = (KX == 0) ? 18 : (KX == 1) ? 2 : 0;
    constexpr int R2HI = (KX == 64) ? 23 : (KX == 65) ? 11 : N2;
    constexpr int R3LO = (KX == 0) ? 6 : 0;
    constexpr int R3HI = (KX == 64) ? 12 : (KX == 65) ? 6 : N3;
    constexpr int MHI  = (KX == 65) ? 2 : 4;

    const int k   = EX ? KX : krt;
    const int t1b = 32 * k - (DP ? 50 : 42);
    const int t2b = 16 * k - (DP ? 22 : 18);
    const int t3b = 8 * k  - (DP ? 8  : 6);

    float A[N1], B[N2], C[N3];

    // ---- level 1: input -> cA1 (A[]) + live cD1 stores; 8-deep shift window ----
    float xw[8];
    #pragma unroll
    for (int j = 0; j < 8; ++j) {
        int g = 2 * (t1b + R1LO) - 6 + j;
        if (EX) g = refl(g, T_LEN);
        xw[j] = inb[(size_t)g * F_DIM];
    }
    #pragma unroll
    for (int r1 = R1LO; r1 < R1HI; ++r1) {
        float a = 0.f, d = 0.f;
        #pragma unroll
        for (int j = 0; j < 8; ++j) { a = fmaf(xw[j], RLO[j], a); d = fmaf(xw[j], RHI[j], d); }
        A[r1] = a;
        const int t1 = t1b + r1;
        if (r1 >= OWN1)
            nt_store(outb + ((size_t)t1 * NB + 4) * F_DIM, d);
        if (r1 + 1 < R1HI) {
            #pragma unroll
            for (int j = 0; j < 6; ++j) xw[j] = xw[j + 2];
            int g6 = 2 * t1 + 2, g7 = 2 * t1 + 3;
            if (EX) { g6 = refl(g6, T_LEN); g7 = refl(g7, T_LEN); }
            xw[6] = inb[(size_t)g6 * F_DIM];
            xw[7] = inb[(size_t)g7 * F_DIM];
        }
    }

    // ---- level 2: cA1 -> cA2 (B[]) + live cD2 stores ----
    #pragma unroll
    for (int r2 = R2LO; r2 < R2HI; ++r2) {
        float a = 0.f, d = 0.f;
        #pragma unroll
        for (int j = 0; j < 8; ++j) {
            const int i1 = EX ? (refl(2 * (t2b + r2) - 6 + j, L1) - t1b) : (2 * r2 + j);
            const float v = A[i1];
            a = fmaf(v, RLO[j], a); d = fmaf(v, RHI[j], d);
        }
        B[r2] = a;
        if (r2 >= OWN2)
            nt_store(outb + ((size_t)(t2b + r2) * NB + 3) * F_DIM, d);
    }

    // ---- level 3: cA2 -> cA3 (C[]) + live cD3 stores ----
    #pragma unroll
    for (int r3 = R3LO; r3 < R3HI; ++r3) {
        float a = 0.f, d = 0.f;
        #pragma unroll
        for (int j = 0; j < 8; ++j) {
            const int i2 = EX ? (refl(2 * (t3b + r3) - 6 + j, L2) - t2b) : (2 * r3 + j);
            const float v = B[i2];
            a = fmaf(v, RLO[j], a); d = fmaf(v, RHI[j], d);
        }
        C[r3] = a;
        if (r3 >= OWN3)
            nt_store(outb + ((size_t)(t3b + r3) * NB + 2) * F_DIM, d);
    }

    // ---- level 4: cA3 -> cA4 (band 0) + cD4 (band 1) stores ----
    #pragma unroll
    for (int m = 0; m < MHI; ++m) {
        float a = 0.f, d = 0.f;
        #pragma unroll
        for (int j = 0; j < 8; ++j) {
            const int i3 = EX ? (refl(2 * (4 * k + m) - 6 + j, L3) - t3b) : (2 * m + j);
            const float v = C[i3];
            a = fmaf(v, RLO[j], a); d = fmaf(v, RHI[j], d);
        }
        const int t4 = 4 * k + m;
        nt_store(outb + ((size_t)t4 * NB + 1) * F_DIM, d);
        nt_store(outb + ((size_t)t4 * NB + 0) * F_DIM, a);
    }
}

extern "C" __global__ __launch_bounds__(256)
void dwt_fused(const float* __restrict__ in, float* __restrict__ out)
{
    const int tid = threadIdx.x;
    const int per = gridDim.x >> 3;                      // bijective XCD swizzle (2048 % 8 == 0)
    const int wg  = (int)(blockIdx.x & 7) * per + (int)(blockIdx.x >> 3);
    const int b   = wg >> 7;                             // 128 slots per batch
    const int j   = wg & 127;

    float* outB = out + (size_t)b * T_LEN * NB * F_DIM;

    if (j < 66) {                                        // live cascade tile
        const float* inb = in + (size_t)b * T_LEN * F_DIM + tid;
        float* outb = outB + tid;
        switch (j) {
            case 0:  cascade<0 >(inb, outb, j); break;
            case 1:  cascade<1 >(inb, outb, j); break;
            case 64: cascade<64>(inb, outb, j); break;
            case 65: cascade<65>(inb, outb, j); break;
            default: cascade<-1>(inb, outb, j); break;   // interior: k in [2,63]
        }
    } else {                                             // zero-fill block
        const int slot = j - 66;                         // [0,62)
        if (slot < 2) {                                  // t in [262,518), 2KB prefix
            const int t0 = 262 + slot * 128;
            fill_zeros<2>(outB, t0, t0 + 128, tid);
        } else if (slot < 8) {                           // t in [518,1029), 3KB prefix
            const int i = slot - 2;
            const int t0 = 518 + i * 86;
            fill_zeros<3>(outB, t0, (t0 + 86 < L2) ? t0 + 86 : L2, tid);
        } else if (slot < 24) {                          // t in [1029,2051), 4KB prefix
            const int i = slot - 8;
            const int t0 = 1029 + i * 64;
            fill_zeros<4>(outB, t0, (t0 + 64 < L1) ? t0 + 64 : L1, tid);
        } else {                                         // t in [2051,4096), full 5KB rows
            const int i = slot - 24;
            const int t0 = 2051 + i * 54;
            fill_zeros<5>(outB, t0, (t0 + 54 < T_LEN) ? t0 + 54 : T_LEN, tid);
        }
    }
}

extern "C" void kernel_launch(void* const* d_in, const int* in_sizes, int n_in,
                              void* d_out, int out_size, void* d_ws, size_t ws_size,
                              hipStream_t stream)
{
    const float* traj = (const float*)d_in[0];
    float* out = (float*)d_out;
    hipLaunchKernelGGL(dwt_fused, dim3(16 * 128), dim3(F_DIM), 0, stream, traj, out);
}